// Round 7
// baseline (80.007 us; speedup 1.0000x reference)
//
#include <hip/hip_runtime.h>
#include <hip/hip_bf16.h>

#define NGRAPH 32
#define NHEAD 8
#define EMB 512
#define NNODES 16384
#define NPG 512
#define LQ 1024
#define PST 520   // padded LDS row stride (ushorts): 2-way bank aliasing (free)

typedef __attribute__((ext_vector_type(8))) short short8;
typedef __attribute__((ext_vector_type(4))) float f32x4;

static __device__ __forceinline__ unsigned short f2bf(float f) {
  union { float f; unsigned u; } v; v.f = f;
  unsigned r = (v.u + 0x7fffu + ((v.u >> 16) & 1u)) >> 16;
  return (unsigned short)r;
}

static __device__ __forceinline__ short8 cvt8(float4 a, float4 b) {
  short8 r;
  r[0] = f2bf(a.x); r[1] = f2bf(a.y); r[2] = f2bf(a.z); r[3] = f2bf(a.w);
  r[4] = f2bf(b.x); r[5] = f2bf(b.y); r[6] = f2bf(b.z); r[7] = f2bf(b.w);
  return r;
}

static __device__ __forceinline__ void gload_lds16(const ushort* g, ushort* l) {
  __builtin_amdgcn_global_load_lds(
      (const __attribute__((address_space(1))) unsigned*)g,
      (__attribute__((address_space(3))) unsigned*)l, 16, 0, 0);
}

// lgkm-only barrier: does NOT drain vmcnt -> global_load_lds prefetches survive
#define BARRIER_LGKM()                                        \
  do {                                                        \
    asm volatile("s_waitcnt lgkmcnt(0)" ::: "memory");        \
    __builtin_amdgcn_s_barrier();                             \
  } while (0)

// =====================================================================
// prep_all: one dispatch for all preprocessing.
//   [0,2048)      : x f32 -> xb bf16 + xbT bf16 (64x64 tiles, XCD-aligned)
//   [2048,2304)   : wv -> wvb
//   [2304,2560)   : wo -> wob
//   2560          : batchcent
//   [2561,2593)   : qpc (standalone, reads raw f32 inputs) -> PCb
// =====================================================================
__global__ __launch_bounds__(256) void prep_all(
    const float* __restrict__ x, const float* __restrict__ wv,
    const float* __restrict__ wo, const float* __restrict__ wq,
    const float* __restrict__ wk, const float* __restrict__ xc,
    const float* __restrict__ bq,
    ushort* __restrict__ xb, ushort* __restrict__ xbT,
    ushort* __restrict__ wvb, ushort* __restrict__ wob,
    ushort* __restrict__ PCb, float* __restrict__ bcent) {
  __shared__ ushort smemU[11776];   // 23 KB, carved per role
  const int b = blockIdx.x;
  const int t = threadIdx.x;

  if (b < 2048) {
    // ---- prep_x: graph g lands on XCD g%8 (matches fused_attn consumer) ----
    ushort* tile = smemU;           // [64][68]
    int xr = b & 7, j = b >> 3;
    int m = j >> 6, r = j & 63;
    int g = xr + 8 * m;
    int bc = r & 7;
    int br = g * 8 + (r >> 3);
    int trr = t >> 4, tc = t & 15;
#pragma unroll
    for (int p = 0; p < 4; ++p) {
      int n = trr + p * 16;
      long gi = (long)(br * 64 + n) * EMB + bc * 64 + tc * 4;
      float4 v = *reinterpret_cast<const float4*>(x + gi);
      ushort4 o;
      o.x = f2bf(v.x); o.y = f2bf(v.y); o.z = f2bf(v.z); o.w = f2bf(v.w);
      *reinterpret_cast<ushort4*>(xb + gi) = o;
      *reinterpret_cast<ushort4*>(&tile[n * 68 + tc * 4]) = o;
    }
    __syncthreads();
#pragma unroll
    for (int p = 0; p < 4; ++p) {
      int e = trr + p * 16;
      int n0 = tc * 4;
      ushort4 o;
      o.x = tile[n0 * 68 + e];       o.y = tile[(n0 + 1) * 68 + e];
      o.z = tile[(n0 + 2) * 68 + e]; o.w = tile[(n0 + 3) * 68 + e];
      *reinterpret_cast<ushort4*>(xbT + (long)(bc * 64 + e) * NNODES + br * 64 + n0) = o;
    }
    return;
  }

  if (b < 2560) {
    // ---- weight conversion ----
    int off = b - 2048;
    const float* src = (off < 256) ? wv : wo;
    ushort* dst = (off < 256) ? wvb : wob;
    off &= 255;
    int i = (off * 256 + t) * 4;
    float4 v = *reinterpret_cast<const float4*>(src + i);
    ushort4 o;
    o.x = f2bf(v.x); o.y = f2bf(v.y); o.z = f2bf(v.z); o.w = f2bf(v.w);
    *reinterpret_cast<ushort4*>(dst + i) = o;
    return;
  }

  if (b == 2560) {
#pragma unroll
    for (int p = 0; p < 4; ++p) bcent[t + p * 256] = (float)((t + p * 256) >> 5);
    return;
  }

  // ---- qpc: PC[h*32+l, qs*128..+128] = (xc·wq_h^T + bq_h) · (0.125·wk_h) ----
  {
    ushort* Qs  = smemU;            // [32][72] bf16
    ushort* WkT = smemU + 2304;     // [128][72] bf16 (transposed, scaled wk slice)
    int qb = b - 2561;
    int h = qb >> 2, qs = qb & 3;
    int w = t >> 6, lane = t & 63;
    int lr = lane & 15, grp = lane >> 4, ko = grp * 8;

    // stage WkT: rows d=h*64..+64, cols k=qs*128..+128, transposed into LDS
    {
      int dl = t >> 2, cq = t & 3;
      const float* wr = wk + (long)(h * 64 + dl) * EMB + qs * 128;
#pragma unroll
      for (int m = 0; m < 8; ++m) {
        int c0 = cq * 32 + m * 4;
        float4 v = *reinterpret_cast<const float4*>(wr + c0);
        WkT[(c0 + 0) * 72 + dl] = f2bf(0.125f * v.x);
        WkT[(c0 + 1) * 72 + dl] = f2bf(0.125f * v.y);
        WkT[(c0 + 2) * 72 + dl] = f2bf(0.125f * v.z);
        WkT[(c0 + 3) * 72 + dl] = f2bf(0.125f * v.w);
      }
    }

    // phase A: Q_h[32,64] = xc[32,512]·wq_h[64,512]^T + bq_h (f32 in, cvt on the fly)
    f32x4 qa[2];
    qa[0] = (f32x4)(0.0f); qa[1] = (f32x4)(0.0f);
#pragma unroll 4
    for (int kk = 0; kk < EMB; kk += 32) {
      const float* xr0 = xc + lr * EMB + kk + ko;
      const float* xr1 = xc + (16 + lr) * EMB + kk + ko;
      const float* wr  = wq + (long)(h * 64 + w * 16 + lr) * EMB + kk + ko;
      short8 a0 = cvt8(*reinterpret_cast<const float4*>(xr0),
                       *reinterpret_cast<const float4*>(xr0 + 4));
      short8 a1 = cvt8(*reinterpret_cast<const float4*>(xr1),
                       *reinterpret_cast<const float4*>(xr1 + 4));
      short8 bb = cvt8(*reinterpret_cast<const float4*>(wr),
                       *reinterpret_cast<const float4*>(wr + 4));
      qa[0] = __builtin_amdgcn_mfma_f32_16x16x32_bf16(a0, bb, qa[0], 0, 0, 0);
      qa[1] = __builtin_amdgcn_mfma_f32_16x16x32_bf16(a1, bb, qa[1], 0, 0, 0);
    }
    float bias = bq[h * 64 + w * 16 + lr];
#pragma unroll
    for (int i = 0; i < 2; ++i)
#pragma unroll
      for (int r = 0; r < 4; ++r)
        Qs[(i * 16 + grp * 4 + r) * 72 + w * 16 + lr] = f2bf(qa[i][r] + bias);
    __syncthreads();

    // phase B: PC slice [32, 128] = Q_h[32,64] · WkT^T (K=64)
    f32x4 pa[2][2];
#pragma unroll
    for (int i = 0; i < 2; ++i)
#pragma unroll
      for (int j = 0; j < 2; ++j) pa[i][j] = (f32x4)(0.0f);
#pragma unroll
    for (int kk = 0; kk < 64; kk += 32) {
      short8 a0 = *reinterpret_cast<const short8*>(&Qs[lr * 72 + kk + ko]);
      short8 a1 = *reinterpret_cast<const short8*>(&Qs[(16 + lr) * 72 + kk + ko]);
#pragma unroll
      for (int j = 0; j < 2; ++j) {
        short8 bb = *reinterpret_cast<const short8*>(
            &WkT[(w * 32 + j * 16 + lr) * 72 + kk + ko]);
        pa[0][j] = __builtin_amdgcn_mfma_f32_16x16x32_bf16(a0, bb, pa[0][j], 0, 0, 0);
        pa[1][j] = __builtin_amdgcn_mfma_f32_16x16x32_bf16(a1, bb, pa[1][j], 0, 0, 0);
      }
    }
#pragma unroll
    for (int i = 0; i < 2; ++i)
#pragma unroll
      for (int j = 0; j < 2; ++j)
#pragma unroll
        for (int r = 0; r < 4; ++r)
          PCb[(long)(h * 32 + i * 16 + grp * 4 + r) * EMB + qs * 128 + w * 32 + j * 16 + lr] =
              f2bf(pa[i][j][r]);
  }
}

// =====================================================================
// fused_attn: per (graph, head) block; QK^T -> softmax -> PV -> ·wv_h^T+bv
// -> out_proj partial (·wo slice) -> atomicAdd into d_out (f32).
// =====================================================================
__global__ __launch_bounds__(1024) void fused_attn(
    const ushort* __restrict__ PCb, const ushort* __restrict__ xb,
    const ushort* __restrict__ xbT, const ushort* __restrict__ wvb,
    const ushort* __restrict__ wob, const float* __restrict__ bvb,
    const float* __restrict__ bob, float* __restrict__ outf) {
  __shared__ ushort PCl[32 * PST];
  __shared__ ushort PBuf[32 * PST];
  __shared__ ushort Bbuf[2][16384];   // [buf][512 rows][32 K]
  __shared__ ushort aoutS[32 * 72];   // per-head attn output bf16
  __shared__ float rmax[32][16];
  __shared__ float rsum[32][16];

  const int g = blockIdx.x & 31, h = blockIdx.x >> 5;  // g%8 == blk%8 -> XCD pinning
  const int t = threadIdx.x, w = t >> 6, lane = t & 63;
  const int lr = lane & 15, grp = lane >> 4;
  const int koU = grp * 8;

  const ushort* xg  = xb  + (long)g * NPG * EMB;
  const ushort* xTg = xbT + g * NPG;

  const int srow0 = w * 32 + (lane >> 2);
  const int spart = lane & 3;

  auto STAGE1 = [&](int c, int db) {
#pragma unroll
    for (int q = 0; q < 2; ++q) {
      int row = srow0 + q * 16;
      int psrc = spart ^ ((row >> 1) & 3);
      gload_lds16(xg + (long)row * EMB + c * 32 + psrc * 8,
                  &Bbuf[db][(w * 32 + q * 16) * 32]);
    }
  };
  auto STAGE3 = [&](int c, int db) {
#pragma unroll
    for (int q = 0; q < 2; ++q) {
      int row = srow0 + q * 16;
      int psrc = spart ^ ((row >> 1) & 3);
      gload_lds16(xTg + (long)row * NNODES + c * 32 + psrc * 8,
                  &Bbuf[db][(w * 32 + q * 16) * 32]);
    }
  };

  STAGE1(0, 0);
  STAGE1(1, 1);
  // stage PC_h into padded LDS
  {
    const ushort* pc = PCb + h * 32 * EMB;
#pragma unroll
    for (int p = 0; p < 2; ++p) {
      int u = t + p * 1024;
      int row = u >> 6, col = (u & 63) * 8;
      *reinterpret_cast<short8*>(&PCl[row * PST + col]) =
          *reinterpret_cast<const short8*>(pc + row * EMB + col);
    }
  }
  BARRIER_LGKM();

  // ---------- phase 1: S = PC_h · X_g^T ; NO barriers ----------
  f32x4 acc[2][2];
#pragma unroll
  for (int i = 0; i < 2; ++i)
#pragma unroll
    for (int j = 0; j < 2; ++j) acc[i][j] = (f32x4)(0.0f);

#pragma unroll
  for (int c = 0; c < 16; ++c) {
    const int db = c & 1;
    asm volatile("s_waitcnt vmcnt(2)" ::: "memory");
    __builtin_amdgcn_sched_barrier(0);
    short8 a0 = *reinterpret_cast<const short8*>(&PCl[lr * PST + c * 32 + koU]);
    short8 a1 = *reinterpret_cast<const short8*>(&PCl[(16 + lr) * PST + c * 32 + koU]);
    short8 bv8[2];
#pragma unroll
    for (int j = 0; j < 2; ++j) {
      int n = w * 32 + j * 16 + lr;
      int psrc = grp ^ ((n >> 1) & 3);
      bv8[j] = *reinterpret_cast<const short8*>(&Bbuf[db][n * 32 + psrc * 8]);
    }
#pragma unroll
    for (int j = 0; j < 2; ++j) {
      acc[0][j] = __builtin_amdgcn_mfma_f32_16x16x32_bf16(a0, bv8[j], acc[0][j], 0, 0, 0);
      acc[1][j] = __builtin_amdgcn_mfma_f32_16x16x32_bf16(a1, bv8[j], acc[1][j], 0, 0, 0);
    }
    __builtin_amdgcn_sched_barrier(0);
    if (c < 14) STAGE1(c + 2, db);
    else        STAGE3(c - 14, db);
  }

  // ---------- phase 2: softmax (cols split 16 ways) ----------
#pragma unroll
  for (int i = 0; i < 2; ++i)
#pragma unroll
    for (int r = 0; r < 4; ++r) {
      float m = fmaxf(acc[i][0][r], acc[i][1][r]);
      m = fmaxf(m, __shfl_xor(m, 1)); m = fmaxf(m, __shfl_xor(m, 2));
      m = fmaxf(m, __shfl_xor(m, 4)); m = fmaxf(m, __shfl_xor(m, 8));
      if (lr == 0) rmax[i * 16 + grp * 4 + r][w] = m;
    }
  BARRIER_LGKM();
#pragma unroll
  for (int i = 0; i < 2; ++i)
#pragma unroll
    for (int r = 0; r < 4; ++r) {
      int row = i * 16 + grp * 4 + r;
      float m = rmax[row][0];
#pragma unroll
      for (int q = 1; q < 16; ++q) m = fmaxf(m, rmax[row][q]);
      float s = 0.f;
#pragma unroll
      for (int j = 0; j < 2; ++j) {
        float e = __expf(acc[i][j][r] - m);
        acc[i][j][r] = e;
        s += e;
      }
      s += __shfl_xor(s, 1); s += __shfl_xor(s, 2);
      s += __shfl_xor(s, 4); s += __shfl_xor(s, 8);
      if (lr == 0) rsum[row][w] = s;
    }
  BARRIER_LGKM();
#pragma unroll
  for (int i = 0; i < 2; ++i)
#pragma unroll
    for (int r = 0; r < 4; ++r) {
      int row = i * 16 + grp * 4 + r;
      float tot = rsum[row][0];
#pragma unroll
      for (int q = 1; q < 16; ++q) tot += rsum[row][q];
      float inv = 1.f / tot;
#pragma unroll
      for (int j = 0; j < 2; ++j)
        PBuf[row * PST + w * 32 + j * 16 + lr] = f2bf(acc[i][j][r] * inv);
    }
  BARRIER_LGKM();   // attn ready in PBuf

  // ---------- phase 3: R = attn · X_g ; NO barriers ----------
  f32x4 acc2[2][2];
#pragma unroll
  for (int i = 0; i < 2; ++i)
#pragma unroll
    for (int j = 0; j < 2; ++j) acc2[i][j] = (f32x4)(0.0f);

#pragma unroll
  for (int c = 0; c < 16; ++c) {
    const int db = c & 1;
    if (c < 15) asm volatile("s_waitcnt vmcnt(2)" ::: "memory");
    else        asm volatile("s_waitcnt vmcnt(0)" ::: "memory");
    __builtin_amdgcn_sched_barrier(0);
    short8 a0 = *reinterpret_cast<const short8*>(&PBuf[lr * PST + c * 32 + koU]);
    short8 a1 = *reinterpret_cast<const short8*>(&PBuf[(16 + lr) * PST + c * 32 + koU]);
    short8 bv8[2];
#pragma unroll
    for (int j = 0; j < 2; ++j) {
      int e = w * 32 + j * 16 + lr;
      int psrc = grp ^ ((e >> 1) & 3);
      bv8[j] = *reinterpret_cast<const short8*>(&Bbuf[db][e * 32 + psrc * 8]);
    }
#pragma unroll
    for (int j = 0; j < 2; ++j) {
      acc2[0][j] = __builtin_amdgcn_mfma_f32_16x16x32_bf16(a0, bv8[j], acc2[0][j], 0, 0, 0);
      acc2[1][j] = __builtin_amdgcn_mfma_f32_16x16x32_bf16(a1, bv8[j], acc2[1][j], 0, 0, 0);
    }
    __builtin_amdgcn_sched_barrier(0);
    if (c < 14) STAGE3(c + 2, db);
  }
  BARRIER_LGKM();   // all waves done reading attn in PBuf

  // write R into PBuf
#pragma unroll
  for (int i = 0; i < 2; ++i)
#pragma unroll
    for (int r = 0; r < 4; ++r) {
      int row = i * 16 + grp * 4 + r;
#pragma unroll
      for (int j = 0; j < 2; ++j)
        PBuf[row * PST + w * 32 + j * 16 + lr] = f2bf(acc2[i][j][r]);
    }
  BARRIER_LGKM();   // R ready

  // ---------- phase 4: aout_h = R · wv_h^T + bv_h  (waves 0..7 -> LDS) ----------
  if (w < 8) {
    int wr = w >> 2, wc = w & 3;
    f32x4 acc3 = (f32x4)(0.0f);
    const ushort* wvh = wvb + (long)(h * 64 + wc * 16) * EMB;
#pragma unroll
    for (int c = 0; c < 16; ++c) {
      short8 a = *reinterpret_cast<const short8*>(&PBuf[(wr * 16 + lr) * PST + c * 32 + koU]);
      short8 b = *reinterpret_cast<const short8*>(wvh + (long)lr * EMB + c * 32 + koU);
      acc3 = __builtin_amdgcn_mfma_f32_16x16x32_bf16(a, b, acc3, 0, 0, 0);
    }
    float bias = bvb[h * 64 + wc * 16 + lr];
#pragma unroll
    for (int r = 0; r < 4; ++r) {
      int row = wr * 16 + grp * 4 + r;
      aoutS[row * 72 + wc * 16 + lr] = f2bf(acc3[r] + bias);
    }
  }
  BARRIER_LGKM();   // aout_h ready

  // ---------- phase 5: out_proj partial: xcent += aout_h · wo[:, h*64..+64]^T ----------
  // wave w -> e-cols w*32..+32 ; K = 64
  f32x4 acc4[2][2];
#pragma unroll
  for (int i = 0; i < 2; ++i)
#pragma unroll
    for (int j = 0; j < 2; ++j) acc4[i][j] = (f32x4)(0.0f);
#pragma unroll
  for (int kk = 0; kk < 64; kk += 32) {
    short8 a0 = *reinterpret_cast<const short8*>(&aoutS[lr * 72 + kk + koU]);
    short8 a1 = *reinterpret_cast<const short8*>(&aoutS[(16 + lr) * 72 + kk + koU]);
#pragma unroll
    for (int j = 0; j < 2; ++j) {
      short8 bb = *reinterpret_cast<const short8*>(
          wob + (long)(w * 32 + j * 16 + lr) * EMB + h * 64 + kk + koU);
      acc4[0][j] = __builtin_amdgcn_mfma_f32_16x16x32_bf16(a0, bb, acc4[0][j], 0, 0, 0);
      acc4[1][j] = __builtin_amdgcn_mfma_f32_16x16x32_bf16(a1, bb, acc4[1][j], 0, 0, 0);
    }
  }
#pragma unroll
  for (int i = 0; i < 2; ++i)
#pragma unroll
    for (int j = 0; j < 2; ++j) {
      int col = w * 32 + j * 16 + lr;
      float bias = (h == 0) ? bob[col] : 0.f;
#pragma unroll
      for (int r = 0; r < 4; ++r) {
        int row = g * 32 + i * 16 + grp * 4 + r;
        unsafeAtomicAdd(&outf[(long)row * EMB + col], acc4[i][j][r] + bias);
      }
    }
}

extern "C" void kernel_launch(void* const* d_in, const int* in_sizes, int n_in,
                              void* d_out, int out_size, void* d_ws, size_t ws_size,
                              hipStream_t stream) {
  const float* x          = (const float*)d_in[0];
  const float* xcent_base = (const float*)d_in[3];
  const float* in_proj_w  = (const float*)d_in[4];
  const float* in_proj_b  = (const float*)d_in[5];
  const float* out_proj_w = (const float*)d_in[6];
  const float* out_proj_b = (const float*)d_in[7];

  char* w = (char*)d_ws;
  ushort* xb   = (ushort*)(w);                 // 16 MiB
  ushort* xbT  = (ushort*)(w + 16777216);      // 16 MiB
  ushort* PCb  = (ushort*)(w + 33554432);      // 256 KiB
  ushort* wvb  = (ushort*)(w + 33816576);      // 512 KiB
  ushort* wob  = (ushort*)(w + 34340864);      // 512 KiB

  const float* wq = in_proj_w;
  const float* wk = in_proj_w + 512 * 512;
  const float* wv = in_proj_w + 1024 * 512;
  const float* bq = in_proj_b;
  const float* bv = in_proj_b + 1024;

  // zero the xcent region (atomic split-K accumulates into it)
  hipMemsetAsync(d_out, 0, (size_t)LQ * EMB * sizeof(float), stream);

  prep_all<<<2593, 256, 0, stream>>>(x, wv, out_proj_w, wq, wk, xcent_base, bq,
                                     xb, xbT, wvb, wob, PCb,
                                     (float*)d_out + (long)LQ * EMB);

  fused_attn<<<256, 1024, 0, stream>>>(PCb, xb, xbT, wvb, wob, bv, out_proj_b,
                                       (float*)d_out);
}

// Round 9
// 65.603 us; speedup vs baseline: 1.2196x; 1.2196x over previous
//
#include <hip/hip_runtime.h>
#include <hip/hip_bf16.h>

#define NGRAPH 32
#define NHEAD 8
#define EMB 512
#define NNODES 16384
#define NPG 512
#define LQ 1024
#define PST 520   // padded LDS row stride (ushorts): quad-aligned, 2-way (free)
#define GCH 262144  // per-graph chunked-slab size in ushorts (16 chunks * 512 rows * 32)

typedef __attribute__((ext_vector_type(8))) short short8;
typedef __attribute__((ext_vector_type(4))) float f32x4;

static __device__ __forceinline__ unsigned short f2bf(float f) {
  union { float f; unsigned u; } v; v.f = f;
  unsigned r = (v.u + 0x7fffu + ((v.u >> 16) & 1u)) >> 16;
  return (unsigned short)r;
}

static __device__ __forceinline__ short8 cvt8(float4 a, float4 b) {
  short8 r;
  r[0] = f2bf(a.x); r[1] = f2bf(a.y); r[2] = f2bf(a.z); r[3] = f2bf(a.w);
  r[4] = f2bf(b.x); r[5] = f2bf(b.y); r[6] = f2bf(b.z); r[7] = f2bf(b.w);
  return r;
}

// async global->LDS: global src is PER-LANE, LDS dest = uniform base + lane*16
static __device__ __forceinline__ void gload_lds16(const ushort* g, ushort* l) {
  __builtin_amdgcn_global_load_lds(
      (const __attribute__((address_space(1))) unsigned*)g,
      (__attribute__((address_space(3))) unsigned*)l, 16, 0, 0);
}

// lgkm-only barrier: does NOT drain vmcnt -> global_load_lds prefetches survive
#define BARRIER_LGKM()                                        \
  do {                                                        \
    asm volatile("s_waitcnt lgkmcnt(0)" ::: "memory");        \
    __builtin_amdgcn_s_barrier();                             \
  } while (0)

// =====================================================================
// prep_all:
//   [0,2048)    : x f32 -> xbC / xbTC (chunked + bank-XOR-swizzled layouts)
//                 xbC [g][kc][node 512][32 K-ushort]  (phase-1 B operand)
//                 xbTC[g][nc][e 512][32 n-ushort]     (phase-3 B operand)
//                 swizzle: memory part pp holds source part pp ^ ((row>>1)&3)
//   [2048,2560) : wv -> wvb ; wo -> wob
//   2560        : batchcent
//   [2561,2593) : qpc (raw f32 inputs) -> PCb
// =====================================================================
__global__ __launch_bounds__(256) void prep_all(
    const float* __restrict__ x, const float* __restrict__ wv,
    const float* __restrict__ wo, const float* __restrict__ wq,
    const float* __restrict__ wk, const float* __restrict__ xc,
    const float* __restrict__ bq,
    ushort* __restrict__ xbC, ushort* __restrict__ xbTC,
    ushort* __restrict__ wvb, ushort* __restrict__ wob,
    ushort* __restrict__ PCb, float* __restrict__ bcent) {
  __shared__ ushort smemU[11776];   // 23 KB, carved per role
  const int b = blockIdx.x;
  const int t = threadIdx.x;

  if (b < 2048) {
    // ---- 64x64 tile of graph g (XCD-pinned: b%8 == g%8 matches consumer) ----
    ushort* tile = smemU;           // [64][72] (144B stride: 16B-aligned rows)
    int xr = b & 7, j = b >> 3;
    int m = j >> 6, r = j & 63;
    int g = xr + 8 * m;
    int bc = r & 7;                 // e-tile   (e0 = bc*64)
    int bl = r >> 3;                // n-tile   (n0 = bl*64, within graph)
    int n0 = bl * 64, e0 = bc * 64;
    int trr = t >> 4, tc = t & 15;
#pragma unroll
    for (int p = 0; p < 4; ++p) {
      int n = trr + p * 16;
      long gi = (long)(g * NPG + n0 + n) * EMB + e0 + tc * 4;
      float4 v = *reinterpret_cast<const float4*>(x + gi);
      ushort4 o;
      o.x = f2bf(v.x); o.y = f2bf(v.y); o.z = f2bf(v.z); o.w = f2bf(v.w);
      *reinterpret_cast<ushort4*>(&tile[n * 72 + tc * 4]) = o;
    }
    __syncthreads();
    {
      int n = t >> 2, pp = t & 3;
      int ng = n0 + n;
      int sp = pp ^ ((ng >> 1) & 3);
      // xbC: chunk kc = K-slice; contiguous 16B stores, swizzled source part
#pragma unroll
      for (int kcq = 0; kcq < 2; ++kcq) {
        int kc = bc * 2 + kcq;
        short8 v = *reinterpret_cast<const short8*>(&tile[n * 72 + kcq * 32 + sp * 8]);
        *reinterpret_cast<short8*>(
            &xbC[(long)g * GCH + kc * 16384 + ng * 32 + pp * 8]) = v;
      }
      // xbTC: chunk nc = node-slice; gather 8 nodes per 16B store (LDS transpose)
      int e = t >> 2;
      int eg = e0 + e;
      int sp2 = (t & 3) ^ ((eg >> 1) & 3);
#pragma unroll
      for (int ncq = 0; ncq < 2; ++ncq) {
        int nc = bl * 2 + ncq;
        ushort tmp[8];
#pragma unroll
        for (int jj = 0; jj < 8; ++jj)
          tmp[jj] = tile[(ncq * 32 + sp2 * 8 + jj) * 72 + e];
        *reinterpret_cast<short8*>(
            &xbTC[(long)g * GCH + nc * 16384 + eg * 32 + (t & 3) * 8]) =
            *reinterpret_cast<short8*>(tmp);
      }
    }
    return;
  }

  if (b < 2560) {
    int off = b - 2048;
    const float* src = (off < 256) ? wv : wo;
    ushort* dst = (off < 256) ? wvb : wob;
    off &= 255;
    int i = (off * 256 + t) * 4;
    float4 v = *reinterpret_cast<const float4*>(src + i);
    ushort4 o;
    o.x = f2bf(v.x); o.y = f2bf(v.y); o.z = f2bf(v.z); o.w = f2bf(v.w);
    *reinterpret_cast<ushort4*>(dst + i) = o;
    return;
  }

  if (b == 2560) {
#pragma unroll
    for (int p = 0; p < 4; ++p) bcent[t + p * 256] = (float)((t + p * 256) >> 5);
    return;
  }

  // ---- qpc: PC[h*32+l, qs*128..+128] = (xc·wq_h^T + bq_h) · (0.125·wk_h) ----
  {
    ushort* Qs  = smemU;            // [32][72]
    ushort* WkT = smemU + 2304;     // [128][72]
    int qb = b - 2561;
    int h = qb >> 2, qs = qb & 3;
    int w = t >> 6, lane = t & 63;
    int lr = lane & 15, grp = lane >> 4, ko = grp * 8;

    {
      int dl = t >> 2, cq = t & 3;
      const float* wr = wk + (long)(h * 64 + dl) * EMB + qs * 128;
#pragma unroll
      for (int m = 0; m < 8; ++m) {
        int c0 = cq * 32 + m * 4;
        float4 v = *reinterpret_cast<const float4*>(wr + c0);
        WkT[(c0 + 0) * 72 + dl] = f2bf(0.125f * v.x);
        WkT[(c0 + 1) * 72 + dl] = f2bf(0.125f * v.y);
        WkT[(c0 + 2) * 72 + dl] = f2bf(0.125f * v.z);
        WkT[(c0 + 3) * 72 + dl] = f2bf(0.125f * v.w);
      }
    }

    f32x4 qa[2];
    qa[0] = (f32x4)(0.0f); qa[1] = (f32x4)(0.0f);
#pragma unroll 4
    for (int kk = 0; kk < EMB; kk += 32) {
      const float* xr0 = xc + lr * EMB + kk + ko;
      const float* xr1 = xc + (16 + lr) * EMB + kk + ko;
      const float* wr  = wq + (long)(h * 64 + w * 16 + lr) * EMB + kk + ko;
      short8 a0 = cvt8(*reinterpret_cast<const float4*>(xr0),
                       *reinterpret_cast<const float4*>(xr0 + 4));
      short8 a1 = cvt8(*reinterpret_cast<const float4*>(xr1),
                       *reinterpret_cast<const float4*>(xr1 + 4));
      short8 bb = cvt8(*reinterpret_cast<const float4*>(wr),
                       *reinterpret_cast<const float4*>(wr + 4));
      qa[0] = __builtin_amdgcn_mfma_f32_16x16x32_bf16(a0, bb, qa[0], 0, 0, 0);
      qa[1] = __builtin_amdgcn_mfma_f32_16x16x32_bf16(a1, bb, qa[1], 0, 0, 0);
    }
    float bias = bq[h * 64 + w * 16 + lr];
#pragma unroll
    for (int i = 0; i < 2; ++i)
#pragma unroll
      for (int r = 0; r < 4; ++r)
        Qs[(i * 16 + grp * 4 + r) * 72 + w * 16 + lr] = f2bf(qa[i][r] + bias);
    __syncthreads();

    f32x4 pa[2][2];
#pragma unroll
    for (int i = 0; i < 2; ++i)
#pragma unroll
      for (int j = 0; j < 2; ++j) pa[i][j] = (f32x4)(0.0f);
#pragma unroll
    for (int kk = 0; kk < 64; kk += 32) {
      short8 a0 = *reinterpret_cast<const short8*>(&Qs[lr * 72 + kk + ko]);
      short8 a1 = *reinterpret_cast<const short8*>(&Qs[(16 + lr) * 72 + kk + ko]);
#pragma unroll
      for (int j = 0; j < 2; ++j) {
        short8 bb = *reinterpret_cast<const short8*>(
            &WkT[(w * 32 + j * 16 + lr) * 72 + kk + ko]);
        pa[0][j] = __builtin_amdgcn_mfma_f32_16x16x32_bf16(a0, bb, pa[0][j], 0, 0, 0);
        pa[1][j] = __builtin_amdgcn_mfma_f32_16x16x32_bf16(a1, bb, pa[1][j], 0, 0, 0);
      }
    }
#pragma unroll
    for (int i = 0; i < 2; ++i)
#pragma unroll
      for (int j = 0; j < 2; ++j)
#pragma unroll
        for (int r = 0; r < 4; ++r)
          PCb[(long)(h * 32 + i * 16 + grp * 4 + r) * EMB + qs * 128 + w * 32 + j * 16 + lr] =
              f2bf(pa[i][j][r]);
  }
}

// =====================================================================
// fused_attn: per (graph, head); 16 waves; barrier-free K-loops with
// fully-coalesced 1KB global_load_lds (per-lane src = base + lane*16B).
// =====================================================================
__global__ __launch_bounds__(1024) void fused_attn(
    const ushort* __restrict__ PCb, const ushort* __restrict__ xbC,
    const ushort* __restrict__ xbTC, const ushort* __restrict__ wvb,
    const float* __restrict__ bvb, ushort* __restrict__ aout) {
  __shared__ ushort PCl[32 * PST];
  __shared__ ushort PBuf[32 * PST];
  __shared__ ushort Bbuf[2][16384];   // [buf][512 rows][32]
  __shared__ float rmax[32][16];
  __shared__ float rsum[32][16];

  const int g = blockIdx.x & 31, h = blockIdx.x >> 5;  // g%8 == blk%8 -> XCD pinning
  const int t = threadIdx.x, w = t >> 6, lane = t & 63;
  const int lr = lane & 15, grp = lane >> 4;
  const int koU = grp * 8;

  const ushort* xgC  = xbC  + (long)g * GCH;
  const ushort* xgTC = xbTC + (long)g * GCH;

  // Wave w stages rows w*32..+32 of chunk c: two 1KB contiguous gload_lds.
  // Global src MUST be per-lane: + lane*8 ushorts (= lane*16 B).  [m104/m108]
  auto STAGE1 = [&](int c, int db) {
#pragma unroll
    for (int q = 0; q < 2; ++q)
      gload_lds16(xgC + c * 16384 + (w * 32 + q * 16) * 32 + lane * 8,
                  &Bbuf[db][(w * 32 + q * 16) * 32]);
  };
  auto STAGE3 = [&](int c, int db) {
#pragma unroll
    for (int q = 0; q < 2; ++q)
      gload_lds16(xgTC + c * 16384 + (w * 32 + q * 16) * 32 + lane * 8,
                  &Bbuf[db][(w * 32 + q * 16) * 32]);
  };

  STAGE1(0, 0);
  STAGE1(1, 1);
  // stage PC_h into padded LDS
  {
    const ushort* pc = PCb + h * 32 * EMB;
#pragma unroll
    for (int p = 0; p < 2; ++p) {
      int u = t + p * 1024;
      int row = u >> 6, col = (u & 63) * 8;
      *reinterpret_cast<short8*>(&PCl[row * PST + col]) =
          *reinterpret_cast<const short8*>(pc + row * EMB + col);
    }
  }
  BARRIER_LGKM();

  // ---------- phase 1: S = PC_h · X_g^T ; NO barriers ----------
  f32x4 acc[2][2];
#pragma unroll
  for (int i = 0; i < 2; ++i)
#pragma unroll
    for (int j = 0; j < 2; ++j) acc[i][j] = (f32x4)(0.0f);

#pragma unroll
  for (int c = 0; c < 16; ++c) {
    const int db = c & 1;
    asm volatile("s_waitcnt vmcnt(2)" ::: "memory");
    __builtin_amdgcn_sched_barrier(0);
    short8 a0 = *reinterpret_cast<const short8*>(&PCl[lr * PST + c * 32 + koU]);
    short8 a1 = *reinterpret_cast<const short8*>(&PCl[(16 + lr) * PST + c * 32 + koU]);
    short8 bv8[2];
#pragma unroll
    for (int j = 0; j < 2; ++j) {
      int n = w * 32 + j * 16 + lr;
      int psrc = grp ^ ((n >> 1) & 3);
      bv8[j] = *reinterpret_cast<const short8*>(&Bbuf[db][n * 32 + psrc * 8]);
    }
#pragma unroll
    for (int j = 0; j < 2; ++j) {
      acc[0][j] = __builtin_amdgcn_mfma_f32_16x16x32_bf16(a0, bv8[j], acc[0][j], 0, 0, 0);
      acc[1][j] = __builtin_amdgcn_mfma_f32_16x16x32_bf16(a1, bv8[j], acc[1][j], 0, 0, 0);
    }
    __builtin_amdgcn_sched_barrier(0);
    if (c < 14) STAGE1(c + 2, db);
    else        STAGE3(c - 14, db);
  }

  // ---------- phase 2: softmax (cols split 16 ways) ----------
#pragma unroll
  for (int i = 0; i < 2; ++i)
#pragma unroll
    for (int r = 0; r < 4; ++r) {
      float m = fmaxf(acc[i][0][r], acc[i][1][r]);
      m = fmaxf(m, __shfl_xor(m, 1)); m = fmaxf(m, __shfl_xor(m, 2));
      m = fmaxf(m, __shfl_xor(m, 4)); m = fmaxf(m, __shfl_xor(m, 8));
      if (lr == 0) rmax[i * 16 + grp * 4 + r][w] = m;
    }
  BARRIER_LGKM();
#pragma unroll
  for (int i = 0; i < 2; ++i)
#pragma unroll
    for (int r = 0; r < 4; ++r) {
      int row = i * 16 + grp * 4 + r;
      float m = rmax[row][0];
#pragma unroll
      for (int q = 1; q < 16; ++q) m = fmaxf(m, rmax[row][q]);
      float s = 0.f;
#pragma unroll
      for (int j = 0; j < 2; ++j) {
        float e = __expf(acc[i][j][r] - m);
        acc[i][j][r] = e;
        s += e;
      }
      s += __shfl_xor(s, 1); s += __shfl_xor(s, 2);
      s += __shfl_xor(s, 4); s += __shfl_xor(s, 8);
      if (lr == 0) rsum[row][w] = s;
    }
  BARRIER_LGKM();
#pragma unroll
  for (int i = 0; i < 2; ++i)
#pragma unroll
    for (int r = 0; r < 4; ++r) {
      int row = i * 16 + grp * 4 + r;
      float tot = rsum[row][0];
#pragma unroll
      for (int q = 1; q < 16; ++q) tot += rsum[row][q];
      float inv = 1.f / tot;
#pragma unroll
      for (int j = 0; j < 2; ++j)
        PBuf[row * PST + w * 32 + j * 16 + lr] = f2bf(acc[i][j][r] * inv);
    }
  BARRIER_LGKM();   // attn ready in PBuf

  // ---------- phase 3: R = attn · X_g ; NO barriers ----------
  f32x4 acc2[2][2];
#pragma unroll
  for (int i = 0; i < 2; ++i)
#pragma unroll
    for (int j = 0; j < 2; ++j) acc2[i][j] = (f32x4)(0.0f);

#pragma unroll
  for (int c = 0; c < 16; ++c) {
    const int db = c & 1;
    if (c < 15) asm volatile("s_waitcnt vmcnt(2)" ::: "memory");
    else        asm volatile("s_waitcnt vmcnt(0)" ::: "memory");
    __builtin_amdgcn_sched_barrier(0);
    short8 a0 = *reinterpret_cast<const short8*>(&PBuf[lr * PST + c * 32 + koU]);
    short8 a1 = *reinterpret_cast<const short8*>(&PBuf[(16 + lr) * PST + c * 32 + koU]);
    short8 bv8[2];
#pragma unroll
    for (int j = 0; j < 2; ++j) {
      int e = w * 32 + j * 16 + lr;
      int psrc = grp ^ ((e >> 1) & 3);
      bv8[j] = *reinterpret_cast<const short8*>(&Bbuf[db][e * 32 + psrc * 8]);
    }
#pragma unroll
    for (int j = 0; j < 2; ++j) {
      acc2[0][j] = __builtin_amdgcn_mfma_f32_16x16x32_bf16(a0, bv8[j], acc2[0][j], 0, 0, 0);
      acc2[1][j] = __builtin_amdgcn_mfma_f32_16x16x32_bf16(a1, bv8[j], acc2[1][j], 0, 0, 0);
    }
    __builtin_amdgcn_sched_barrier(0);
    if (c < 14) STAGE3(c + 2, db);
  }
  BARRIER_LGKM();   // all waves done reading attn in PBuf

  // write R into PBuf
#pragma unroll
  for (int i = 0; i < 2; ++i)
#pragma unroll
    for (int r = 0; r < 4; ++r) {
      int row = i * 16 + grp * 4 + r;
#pragma unroll
      for (int j = 0; j < 2; ++j)
        PBuf[row * PST + w * 32 + j * 16 + lr] = f2bf(acc2[i][j][r]);
    }
  BARRIER_LGKM();   // R ready

  // ---------- phase 4: aout_h = R · wv_h^T + bv_h  (waves 0..7) ----------
  if (w < 8) {
    int wr = w >> 2, wc = w & 3;
    f32x4 acc3 = (f32x4)(0.0f);
    const ushort* wvh = wvb + (long)(h * 64 + wc * 16) * EMB;
#pragma unroll
    for (int c = 0; c < 16; ++c) {
      short8 a = *reinterpret_cast<const short8*>(&PBuf[(wr * 16 + lr) * PST + c * 32 + koU]);
      short8 b = *reinterpret_cast<const short8*>(wvh + (long)lr * EMB + c * 32 + koU);
      acc3 = __builtin_amdgcn_mfma_f32_16x16x32_bf16(a, b, acc3, 0, 0, 0);
    }
    float bias = bvb[h * 64 + wc * 16 + lr];
#pragma unroll
    for (int r = 0; r < 4; ++r) {
      int row = wr * 16 + grp * 4 + r;
      aout[(long)(g * 32 + row) * EMB + h * 64 + wc * 16 + lr] = f2bf(acc3[r] + bias);
    }
  }
}

// ---- generic C = A·B^T (+bias) GEMM (out_proj only) ----
template <int KK, int FM, int FN, int WM, int WN, bool OUT_BF16, bool HAS_BIAS>
__global__ void gemm_abt(const ushort* __restrict__ A, const ushort* __restrict__ Bm,
                         void* __restrict__ C, const float* __restrict__ bias,
                         int lda, int ldb, int ldc) {
  int tid = threadIdx.x;
  int wave = tid >> 6, lane = tid & 63;
  int wr = wave / WN, wc = wave % WN;
  int rowBase = blockIdx.y * (WM * FM * 16) + wr * FM * 16;
  int colBase = blockIdx.x * (WN * FN * 16) + wc * FN * 16;
  int lr = lane & 15;
  int ko = (lane >> 4) * 8;

  f32x4 acc[FM][FN];
#pragma unroll
  for (int i = 0; i < FM; ++i)
#pragma unroll
    for (int j = 0; j < FN; ++j) acc[i][j] = (f32x4)(0.0f);

#pragma unroll 8
  for (int kk = 0; kk < KK; kk += 32) {
    short8 av[FM], bv[FN];
#pragma unroll
    for (int i = 0; i < FM; ++i)
      av[i] = *reinterpret_cast<const short8*>(A + (long)(rowBase + i * 16 + lr) * lda + kk + ko);
#pragma unroll
    for (int j = 0; j < FN; ++j)
      bv[j] = *reinterpret_cast<const short8*>(Bm + (long)(colBase + j * 16 + lr) * ldb + kk + ko);
#pragma unroll
    for (int i = 0; i < FM; ++i)
#pragma unroll
      for (int j = 0; j < FN; ++j)
        acc[i][j] = __builtin_amdgcn_mfma_f32_16x16x32_bf16(av[i], bv[j], acc[i][j], 0, 0, 0);
  }

  int or0 = (lane >> 4) * 4;
#pragma unroll
  for (int i = 0; i < FM; ++i) {
#pragma unroll
    for (int j = 0; j < FN; ++j) {
      int col = colBase + j * 16 + lr;
      float bval = HAS_BIAS ? bias[col] : 0.f;
#pragma unroll
      for (int r = 0; r < 4; ++r) {
        int row = rowBase + i * 16 + or0 + r;
        float v = acc[i][j][r] + bval;
        if (OUT_BF16)
          ((ushort*)C)[(long)row * ldc + col] = f2bf(v);
        else
          ((float*)C)[(long)row * ldc + col] = v;
      }
    }
  }
}

extern "C" void kernel_launch(void* const* d_in, const int* in_sizes, int n_in,
                              void* d_out, int out_size, void* d_ws, size_t ws_size,
                              hipStream_t stream) {
  const float* x          = (const float*)d_in[0];
  const float* xcent_base = (const float*)d_in[3];
  const float* in_proj_w  = (const float*)d_in[4];
  const float* in_proj_b  = (const float*)d_in[5];
  const float* out_proj_w = (const float*)d_in[6];
  const float* out_proj_b = (const float*)d_in[7];

  char* w = (char*)d_ws;
  ushort* xbC  = (ushort*)(w);                 // 16 MiB
  ushort* xbTC = (ushort*)(w + 16777216);      // 16 MiB
  ushort* PCb  = (ushort*)(w + 33554432);      // 256 KiB
  ushort* wvb  = (ushort*)(w + 33816576);      // 512 KiB
  ushort* wob  = (ushort*)(w + 34340864);      // 512 KiB
  ushort* aout = (ushort*)(w + 34865152);      // 1 MiB

  const float* wq = in_proj_w;
  const float* wk = in_proj_w + 512 * 512;
  const float* wv = in_proj_w + 1024 * 512;
  const float* bq = in_proj_b;
  const float* bv = in_proj_b + 1024;

  prep_all<<<2593, 256, 0, stream>>>(x, wv, out_proj_w, wq, wk, xcent_base, bq,
                                     xbC, xbTC, wvb, wob, PCb,
                                     (float*)d_out + (long)LQ * EMB);

  fused_attn<<<256, 1024, 0, stream>>>(PCb, xbC, xbTC, wvb, bv, aout);

  gemm_abt<512, 1, 2, 2, 2, false, true><<<dim3(8, 32, 1), 256, 0, stream>>>(
      aout, wob, d_out, out_proj_b, 512, 512, 512);
}

// Round 10
// 57.117 us; speedup vs baseline: 1.4008x; 1.1486x over previous
//
#include <hip/hip_runtime.h>
#include <hip/hip_bf16.h>

#define NGRAPH 32
#define NHEAD 8
#define EMB 512
#define NNODES 16384
#define NPG 512
#define LQ 1024
#define PST 520   // padded LDS row stride (ushorts): quad-aligned, 2-way (free)
#define GCH 262144  // per-graph chunked-slab size in ushorts (16 chunks * 512 rows * 32)

typedef __attribute__((ext_vector_type(8))) short short8;
typedef __attribute__((ext_vector_type(4))) float f32x4;

static __device__ __forceinline__ unsigned short f2bf(float f) {
  union { float f; unsigned u; } v; v.f = f;
  unsigned r = (v.u + 0x7fffu + ((v.u >> 16) & 1u)) >> 16;
  return (unsigned short)r;
}

static __device__ __forceinline__ short8 cvt8(float4 a, float4 b) {
  short8 r;
  r[0] = f2bf(a.x); r[1] = f2bf(a.y); r[2] = f2bf(a.z); r[3] = f2bf(a.w);
  r[4] = f2bf(b.x); r[5] = f2bf(b.y); r[6] = f2bf(b.z); r[7] = f2bf(b.w);
  return r;
}

// async global->LDS: global src is PER-LANE, LDS dest = uniform base + lane*16
static __device__ __forceinline__ void gload_lds16(const ushort* g, ushort* l) {
  __builtin_amdgcn_global_load_lds(
      (const __attribute__((address_space(1))) unsigned*)g,
      (__attribute__((address_space(3))) unsigned*)l, 16, 0, 0);
}

// lgkm-only barrier: does NOT drain vmcnt -> global_load_lds prefetches survive
#define BARRIER_LGKM()                                        \
  do {                                                        \
    asm volatile("s_waitcnt lgkmcnt(0)" ::: "memory");        \
    __builtin_amdgcn_s_barrier();                             \
  } while (0)

// =====================================================================
// prep_all (grid 1569):
//   [0,32)      : qpc (FIRST -> overlaps streaming, no serial tail) -> PCb
//   [32,1056)   : x f32 -> xbC / xbTC ; 128x64 slab per block (2 tiles,
//                 8 loads in flight), jj-rotated gather (bank-spread)
//   [1056,1568) : wv -> wvb ; wo -> wob
//   1568        : batchcent
// =====================================================================
__global__ __launch_bounds__(256) void prep_all(
    const float* __restrict__ x, const float* __restrict__ wv,
    const float* __restrict__ wo, const float* __restrict__ wq,
    const float* __restrict__ wk, const float* __restrict__ xc,
    const float* __restrict__ bq,
    ushort* __restrict__ xbC, ushort* __restrict__ xbTC,
    ushort* __restrict__ wvb, ushort* __restrict__ wob,
    ushort* __restrict__ PCb, float* __restrict__ bcent) {
  __shared__ ushort smemU[11776];   // 23 KB, carved per role
  const int b = blockIdx.x;
  const int t = threadIdx.x;

  if (b < 32) {
    // ---- qpc: PC[h*32+l, qs*128..+128] = (xc·wq_h^T + bq_h) · (0.125·wk_h) ----
    ushort* Qs  = smemU;            // [32][72]
    ushort* WkT = smemU + 2304;     // [128][72]
    int h = b >> 2, qs = b & 3;
    int w = t >> 6, lane = t & 63;
    int lr = lane & 15, grp = lane >> 4, ko = grp * 8;

    {
      int dl = t >> 2, cq = t & 3;
      const float* wr = wk + (long)(h * 64 + dl) * EMB + qs * 128;
#pragma unroll
      for (int m = 0; m < 8; ++m) {
        int c0 = cq * 32 + m * 4;
        float4 v = *reinterpret_cast<const float4*>(wr + c0);
        WkT[(c0 + 0) * 72 + dl] = f2bf(0.125f * v.x);
        WkT[(c0 + 1) * 72 + dl] = f2bf(0.125f * v.y);
        WkT[(c0 + 2) * 72 + dl] = f2bf(0.125f * v.z);
        WkT[(c0 + 3) * 72 + dl] = f2bf(0.125f * v.w);
      }
    }

    f32x4 qa[2];
    qa[0] = (f32x4)(0.0f); qa[1] = (f32x4)(0.0f);
#pragma unroll 4
    for (int kk = 0; kk < EMB; kk += 32) {
      const float* xr0 = xc + lr * EMB + kk + ko;
      const float* xr1 = xc + (16 + lr) * EMB + kk + ko;
      const float* wr  = wq + (long)(h * 64 + w * 16 + lr) * EMB + kk + ko;
      short8 a0 = cvt8(*reinterpret_cast<const float4*>(xr0),
                       *reinterpret_cast<const float4*>(xr0 + 4));
      short8 a1 = cvt8(*reinterpret_cast<const float4*>(xr1),
                       *reinterpret_cast<const float4*>(xr1 + 4));
      short8 bb = cvt8(*reinterpret_cast<const float4*>(wr),
                       *reinterpret_cast<const float4*>(wr + 4));
      qa[0] = __builtin_amdgcn_mfma_f32_16x16x32_bf16(a0, bb, qa[0], 0, 0, 0);
      qa[1] = __builtin_amdgcn_mfma_f32_16x16x32_bf16(a1, bb, qa[1], 0, 0, 0);
    }
    float bias = bq[h * 64 + w * 16 + lr];
#pragma unroll
    for (int i = 0; i < 2; ++i)
#pragma unroll
      for (int r = 0; r < 4; ++r)
        Qs[(i * 16 + grp * 4 + r) * 72 + w * 16 + lr] = f2bf(qa[i][r] + bias);
    __syncthreads();

    f32x4 pa[2][2];
#pragma unroll
    for (int i = 0; i < 2; ++i)
#pragma unroll
      for (int j = 0; j < 2; ++j) pa[i][j] = (f32x4)(0.0f);
#pragma unroll
    for (int kk = 0; kk < 64; kk += 32) {
      short8 a0 = *reinterpret_cast<const short8*>(&Qs[lr * 72 + kk + ko]);
      short8 a1 = *reinterpret_cast<const short8*>(&Qs[(16 + lr) * 72 + kk + ko]);
#pragma unroll
      for (int j = 0; j < 2; ++j) {
        short8 bb = *reinterpret_cast<const short8*>(
            &WkT[(w * 32 + j * 16 + lr) * 72 + kk + ko]);
        pa[0][j] = __builtin_amdgcn_mfma_f32_16x16x32_bf16(a0, bb, pa[0][j], 0, 0, 0);
        pa[1][j] = __builtin_amdgcn_mfma_f32_16x16x32_bf16(a1, bb, pa[1][j], 0, 0, 0);
      }
    }
#pragma unroll
    for (int i = 0; i < 2; ++i)
#pragma unroll
      for (int j = 0; j < 2; ++j)
#pragma unroll
        for (int r = 0; r < 4; ++r)
          PCb[(long)(h * 32 + i * 16 + grp * 4 + r) * EMB + qs * 128 + w * 32 + j * 16 + lr] =
              f2bf(pa[i][j][r]);
    return;
  }

  if (b < 1056) {
    // ---- x slab: 128 nodes x 64 E of graph g (b%8 == g%8 -> XCD pinned) ----
    ushort* tileA = smemU;            // [64][72]
    ushort* tileB = smemU + 4608;     // [64][72]
    int local = b - 32;
    int xr = local & 7, j = local >> 3;   // j 0..127
    int m = j >> 5, r = j & 31;
    int g = xr + 8 * m;
    int bc = r & 7;                   // e-tile (e0 = bc*64)
    int bl = r >> 3;                  // n-slab of 128 (0..3)
    int n0 = bl * 128, e0 = bc * 64;
    int trr = t >> 4, tc = t & 15;

    // issue all 8 loads up-front (32 KB in flight per block)
    float4 vA[4], vB[4];
#pragma unroll
    for (int p = 0; p < 4; ++p)
      vA[p] = *reinterpret_cast<const float4*>(
          x + (long)(g * NPG + n0 + trr + p * 16) * EMB + e0 + tc * 4);
#pragma unroll
    for (int p = 0; p < 4; ++p)
      vB[p] = *reinterpret_cast<const float4*>(
          x + (long)(g * NPG + n0 + 64 + trr + p * 16) * EMB + e0 + tc * 4);
#pragma unroll
    for (int p = 0; p < 4; ++p) {
      int n = trr + p * 16;
      ushort4 o;
      o.x = f2bf(vA[p].x); o.y = f2bf(vA[p].y); o.z = f2bf(vA[p].z); o.w = f2bf(vA[p].w);
      *reinterpret_cast<ushort4*>(&tileA[n * 72 + tc * 4]) = o;
    }
#pragma unroll
    for (int p = 0; p < 4; ++p) {
      int n = trr + p * 16;
      ushort4 o;
      o.x = f2bf(vB[p].x); o.y = f2bf(vB[p].y); o.z = f2bf(vB[p].z); o.w = f2bf(vB[p].w);
      *reinterpret_cast<ushort4*>(&tileB[n * 72 + tc * 4]) = o;
    }
    __syncthreads();

    // xbC: kc = e-chunk; contiguous 16B stores, swizzled source part
    {
      int n = t >> 2, pp = t & 3;
#pragma unroll
      for (int tb = 0; tb < 2; ++tb) {
        const ushort* tile = tb ? tileB : tileA;
        int ng = n0 + tb * 64 + n;
        int sp = pp ^ ((ng >> 1) & 3);
#pragma unroll
        for (int kcq = 0; kcq < 2; ++kcq) {
          int kc = bc * 2 + kcq;
          short8 v = *reinterpret_cast<const short8*>(&tile[n * 72 + kcq * 32 + sp * 8]);
          *reinterpret_cast<short8*>(
              &xbC[(long)g * GCH + kc * 16384 + ng * 32 + pp * 8]) = v;
        }
      }
    }
    // xbTC: nc = node-chunk; jj-rotated gather (bank-spread), contiguous stores
    {
      int e = t >> 2;
      int eg = e0 + e;
      int sp2 = (t & 3) ^ ((eg >> 1) & 3);
      int rot = t & 7;
#pragma unroll
      for (int tb = 0; tb < 2; ++tb) {
        const ushort* tile = tb ? tileB : tileA;
#pragma unroll
        for (int ncq = 0; ncq < 2; ++ncq) {
          int nc = bl * 4 + tb * 2 + ncq;
          ushort tmp[8];
#pragma unroll
          for (int k = 0; k < 8; ++k) {
            int jj = (k + rot) & 7;
            tmp[jj] = tile[(ncq * 32 + sp2 * 8 + jj) * 72 + e];
          }
          *reinterpret_cast<short8*>(
              &xbTC[(long)g * GCH + nc * 16384 + eg * 32 + (t & 3) * 8]) =
              *reinterpret_cast<short8*>(tmp);
        }
      }
    }
    return;
  }

  if (b < 1568) {
    int off = b - 1056;
    const float* src = (off < 256) ? wv : wo;
    ushort* dst = (off < 256) ? wvb : wob;
    off &= 255;
    int i = (off * 256 + t) * 4;
    float4 v = *reinterpret_cast<const float4*>(src + i);
    ushort4 o;
    o.x = f2bf(v.x); o.y = f2bf(v.y); o.z = f2bf(v.z); o.w = f2bf(v.w);
    *reinterpret_cast<ushort4*>(dst + i) = o;
    return;
  }

  // b == 1568: batchcent
#pragma unroll
  for (int p = 0; p < 4; ++p) bcent[t + p * 256] = (float)((t + p * 256) >> 5);
}

// =====================================================================
// fused_attn: per (graph, head); 16 waves; barrier-free K-loops with
// fully-coalesced 1KB global_load_lds (per-lane src = base + lane*16B).
// =====================================================================
__global__ __launch_bounds__(1024) void fused_attn(
    const ushort* __restrict__ PCb, const ushort* __restrict__ xbC,
    const ushort* __restrict__ xbTC, const ushort* __restrict__ wvb,
    const float* __restrict__ bvb, ushort* __restrict__ aout) {
  __shared__ ushort PCl[32 * PST];
  __shared__ ushort PBuf[32 * PST];
  __shared__ ushort Bbuf[2][16384];   // [buf][512 rows][32]
  __shared__ float rmax[32][16];
  __shared__ float rsum[32][16];

  const int g = blockIdx.x & 31, h = blockIdx.x >> 5;  // g%8 == blk%8 -> XCD pinning
  const int t = threadIdx.x, w = t >> 6, lane = t & 63;
  const int lr = lane & 15, grp = lane >> 4;
  const int koU = grp * 8;

  const ushort* xgC  = xbC  + (long)g * GCH;
  const ushort* xgTC = xbTC + (long)g * GCH;

  auto STAGE1 = [&](int c, int db) {
#pragma unroll
    for (int q = 0; q < 2; ++q)
      gload_lds16(xgC + c * 16384 + (w * 32 + q * 16) * 32 + lane * 8,
                  &Bbuf[db][(w * 32 + q * 16) * 32]);
  };
  auto STAGE3 = [&](int c, int db) {
#pragma unroll
    for (int q = 0; q < 2; ++q)
      gload_lds16(xgTC + c * 16384 + (w * 32 + q * 16) * 32 + lane * 8,
                  &Bbuf[db][(w * 32 + q * 16) * 32]);
  };

  STAGE1(0, 0);
  STAGE1(1, 1);
  // stage PC_h into padded LDS
  {
    const ushort* pc = PCb + h * 32 * EMB;
#pragma unroll
    for (int p = 0; p < 2; ++p) {
      int u = t + p * 1024;
      int row = u >> 6, col = (u & 63) * 8;
      *reinterpret_cast<short8*>(&PCl[row * PST + col]) =
          *reinterpret_cast<const short8*>(pc + row * EMB + col);
    }
  }
  BARRIER_LGKM();

  // ---------- phase 1: S = PC_h · X_g^T ; NO barriers ----------
  f32x4 acc[2][2];
#pragma unroll
  for (int i = 0; i < 2; ++i)
#pragma unroll
    for (int j = 0; j < 2; ++j) acc[i][j] = (f32x4)(0.0f);

#pragma unroll
  for (int c = 0; c < 16; ++c) {
    const int db = c & 1;
    asm volatile("s_waitcnt vmcnt(2)" ::: "memory");
    __builtin_amdgcn_sched_barrier(0);
    short8 a0 = *reinterpret_cast<const short8*>(&PCl[lr * PST + c * 32 + koU]);
    short8 a1 = *reinterpret_cast<const short8*>(&PCl[(16 + lr) * PST + c * 32 + koU]);
    short8 bv8[2];
#pragma unroll
    for (int j = 0; j < 2; ++j) {
      int n = w * 32 + j * 16 + lr;
      int psrc = grp ^ ((n >> 1) & 3);
      bv8[j] = *reinterpret_cast<const short8*>(&Bbuf[db][n * 32 + psrc * 8]);
    }
#pragma unroll
    for (int j = 0; j < 2; ++j) {
      acc[0][j] = __builtin_amdgcn_mfma_f32_16x16x32_bf16(a0, bv8[j], acc[0][j], 0, 0, 0);
      acc[1][j] = __builtin_amdgcn_mfma_f32_16x16x32_bf16(a1, bv8[j], acc[1][j], 0, 0, 0);
    }
    __builtin_amdgcn_sched_barrier(0);
    if (c < 14) STAGE1(c + 2, db);
    else        STAGE3(c - 14, db);
  }

  // ---------- phase 2: softmax (cols split 16 ways) ----------
#pragma unroll
  for (int i = 0; i < 2; ++i)
#pragma unroll
    for (int r = 0; r < 4; ++r) {
      float m = fmaxf(acc[i][0][r], acc[i][1][r]);
      m = fmaxf(m, __shfl_xor(m, 1)); m = fmaxf(m, __shfl_xor(m, 2));
      m = fmaxf(m, __shfl_xor(m, 4)); m = fmaxf(m, __shfl_xor(m, 8));
      if (lr == 0) rmax[i * 16 + grp * 4 + r][w] = m;
    }
  BARRIER_LGKM();
#pragma unroll
  for (int i = 0; i < 2; ++i)
#pragma unroll
    for (int r = 0; r < 4; ++r) {
      int row = i * 16 + grp * 4 + r;
      float m = rmax[row][0];
#pragma unroll
      for (int q = 1; q < 16; ++q) m = fmaxf(m, rmax[row][q]);
      float s = 0.f;
#pragma unroll
      for (int j = 0; j < 2; ++j) {
        float e = __expf(acc[i][j][r] - m);
        acc[i][j][r] = e;
        s += e;
      }
      s += __shfl_xor(s, 1); s += __shfl_xor(s, 2);
      s += __shfl_xor(s, 4); s += __shfl_xor(s, 8);
      if (lr == 0) rsum[row][w] = s;
    }
  BARRIER_LGKM();
#pragma unroll
  for (int i = 0; i < 2; ++i)
#pragma unroll
    for (int r = 0; r < 4; ++r) {
      int row = i * 16 + grp * 4 + r;
      float tot = rsum[row][0];
#pragma unroll
      for (int q = 1; q < 16; ++q) tot += rsum[row][q];
      float inv = 1.f / tot;
#pragma unroll
      for (int j = 0; j < 2; ++j)
        PBuf[row * PST + w * 32 + j * 16 + lr] = f2bf(acc[i][j][r] * inv);
    }
  BARRIER_LGKM();   // attn ready in PBuf

  // ---------- phase 3: R = attn · X_g ; NO barriers ----------
  f32x4 acc2[2][2];
#pragma unroll
  for (int i = 0; i < 2; ++i)
#pragma unroll
    for (int j = 0; j < 2; ++j) acc2[i][j] = (f32x4)(0.0f);

#pragma unroll
  for (int c = 0; c < 16; ++c) {
    const int db = c & 1;
    if (c < 15) asm volatile("s_waitcnt vmcnt(2)" ::: "memory");
    else        asm volatile("s_waitcnt vmcnt(0)" ::: "memory");
    __builtin_amdgcn_sched_barrier(0);
    short8 a0 = *reinterpret_cast<const short8*>(&PBuf[lr * PST + c * 32 + koU]);
    short8 a1 = *reinterpret_cast<const short8*>(&PBuf[(16 + lr) * PST + c * 32 + koU]);
    short8 bv8[2];
#pragma unroll
    for (int j = 0; j < 2; ++j) {
      int e = w * 32 + j * 16 + lr;
      int psrc = grp ^ ((e >> 1) & 3);
      bv8[j] = *reinterpret_cast<const short8*>(&Bbuf[db][e * 32 + psrc * 8]);
    }
#pragma unroll
    for (int j = 0; j < 2; ++j) {
      acc2[0][j] = __builtin_amdgcn_mfma_f32_16x16x32_bf16(a0, bv8[j], acc2[0][j], 0, 0, 0);
      acc2[1][j] = __builtin_amdgcn_mfma_f32_16x16x32_bf16(a1, bv8[j], acc2[1][j], 0, 0, 0);
    }
    __builtin_amdgcn_sched_barrier(0);
    if (c < 14) STAGE3(c + 2, db);
  }
  BARRIER_LGKM();   // all waves done reading attn in PBuf

  // write R into PBuf
#pragma unroll
  for (int i = 0; i < 2; ++i)
#pragma unroll
    for (int r = 0; r < 4; ++r) {
      int row = i * 16 + grp * 4 + r;
#pragma unroll
      for (int j = 0; j < 2; ++j)
        PBuf[row * PST + w * 32 + j * 16 + lr] = f2bf(acc2[i][j][r]);
    }
  BARRIER_LGKM();   // R ready

  // ---------- phase 4: aout_h = R · wv_h^T + bv_h  (waves 0..7) ----------
  if (w < 8) {
    int wr = w >> 2, wc = w & 3;
    f32x4 acc3 = (f32x4)(0.0f);
    const ushort* wvh = wvb + (long)(h * 64 + wc * 16) * EMB;
#pragma unroll
    for (int c = 0; c < 16; ++c) {
      short8 a = *reinterpret_cast<const short8*>(&PBuf[(wr * 16 + lr) * PST + c * 32 + koU]);
      short8 b = *reinterpret_cast<const short8*>(wvh + (long)lr * EMB + c * 32 + koU);
      acc3 = __builtin_amdgcn_mfma_f32_16x16x32_bf16(a, b, acc3, 0, 0, 0);
    }
    float bias = bvb[h * 64 + wc * 16 + lr];
#pragma unroll
    for (int r = 0; r < 4; ++r) {
      int row = wr * 16 + grp * 4 + r;
      aout[(long)(g * 32 + row) * EMB + h * 64 + wc * 16 + lr] = f2bf(acc3[r] + bias);
    }
  }
}

// ---- generic C = A·B^T (+bias) GEMM (out_proj only) ----
template <int KK, int FM, int FN, int WM, int WN, bool OUT_BF16, bool HAS_BIAS>
__global__ void gemm_abt(const ushort* __restrict__ A, const ushort* __restrict__ Bm,
                         void* __restrict__ C, const float* __restrict__ bias,
                         int lda, int ldb, int ldc) {
  int tid = threadIdx.x;
  int wave = tid >> 6, lane = tid & 63;
  int wr = wave / WN, wc = wave % WN;
  int rowBase = blockIdx.y * (WM * FM * 16) + wr * FM * 16;
  int colBase = blockIdx.x * (WN * FN * 16) + wc * FN * 16;
  int lr = lane & 15;
  int ko = (lane >> 4) * 8;

  f32x4 acc[FM][FN];
#pragma unroll
  for (int i = 0; i < FM; ++i)
#pragma unroll
    for (int j = 0; j < FN; ++j) acc[i][j] = (f32x4)(0.0f);

#pragma unroll 8
  for (int kk = 0; kk < KK; kk += 32) {
    short8 av[FM], bv[FN];
#pragma unroll
    for (int i = 0; i < FM; ++i)
      av[i] = *reinterpret_cast<const short8*>(A + (long)(rowBase + i * 16 + lr) * lda + kk + ko);
#pragma unroll
    for (int j = 0; j < FN; ++j)
      bv[j] = *reinterpret_cast<const short8*>(Bm + (long)(colBase + j * 16 + lr) * ldb + kk + ko);
#pragma unroll
    for (int i = 0; i < FM; ++i)
#pragma unroll
      for (int j = 0; j < FN; ++j)
        acc[i][j] = __builtin_amdgcn_mfma_f32_16x16x32_bf16(av[i], bv[j], acc[i][j], 0, 0, 0);
  }

  int or0 = (lane >> 4) * 4;
#pragma unroll
  for (int i = 0; i < FM; ++i) {
#pragma unroll
    for (int j = 0; j < FN; ++j) {
      int col = colBase + j * 16 + lr;
      float bval = HAS_BIAS ? bias[col] : 0.f;
#pragma unroll
      for (int r = 0; r < 4; ++r) {
        int row = rowBase + i * 16 + or0 + r;
        float v = acc[i][j][r] + bval;
        if (OUT_BF16)
          ((ushort*)C)[(long)row * ldc + col] = f2bf(v);
        else
          ((float*)C)[(long)row * ldc + col] = v;
      }
    }
  }
}

extern "C" void kernel_launch(void* const* d_in, const int* in_sizes, int n_in,
                              void* d_out, int out_size, void* d_ws, size_t ws_size,
                              hipStream_t stream) {
  const float* x          = (const float*)d_in[0];
  const float* xcent_base = (const float*)d_in[3];
  const float* in_proj_w  = (const float*)d_in[4];
  const float* in_proj_b  = (const float*)d_in[5];
  const float* out_proj_w = (const float*)d_in[6];
  const float* out_proj_b = (const float*)d_in[7];

  char* w = (char*)d_ws;
  ushort* xbC  = (ushort*)(w);                 // 16 MiB
  ushort* xbTC = (ushort*)(w + 16777216);      // 16 MiB
  ushort* PCb  = (ushort*)(w + 33554432);      // 256 KiB
  ushort* wvb  = (ushort*)(w + 33816576);      // 512 KiB
  ushort* wob  = (ushort*)(w + 34340864);      // 512 KiB
  ushort* aout = (ushort*)(w + 34865152);      // 1 MiB

  const float* wq = in_proj_w;
  const float* wk = in_proj_w + 512 * 512;
  const float* wv = in_proj_w + 1024 * 512;
  const float* bq = in_proj_b;
  const float* bv = in_proj_b + 1024;

  prep_all<<<1569, 256, 0, stream>>>(x, wv, out_proj_w, wq, wk, xcent_base, bq,
                                     xbC, xbTC, wvb, wob, PCb,
                                     (float*)d_out + (long)LQ * EMB);

  fused_attn<<<256, 1024, 0, stream>>>(PCb, xbC, xbTC, wvb, bv, aout);

  gemm_abt<512, 1, 2, 2, 2, false, true><<<dim3(8, 32, 1), 256, 0, stream>>>(
      aout, wob, d_out, out_proj_b, 512, 512, 512);
}